// Round 4
// baseline (3025.192 us; speedup 1.0000x reference)
//
#include <hip/hip_runtime.h>
#include <float.h>

// Sparsemax attention, streaming 2-pass MFMA.
// B=2,H=16,S=2048,D=64 fp32, temperature 8.
// Block = 32 q-rows (512 thr, 8 waves); wave w owns cols [w*256,(w+1)*256).
// Pass A: stream 16 col-tiles of mfma_f32_16x16x32_bf16, keep only running
//   row-max (acc is transient per tile -> low VGPR, high occupancy).
// Pass B: re-stream the same MFMAs, collect candidates {raw > rawmax-8.5}
//   into per-row LDS lists (support provably inside; bf16 err << 0.5 margin).
// Phase 2 (per wave, 4 rows): fp32 cooperative recompute of candidates,
//   Michelot tau (exact, finite), sparse PV via LDS broadcast. Dense fp32
//   fallback on CAP overflow (never hit for Gaussian data; correctness only).

#define S_LEN 2048
#define DHEAD 64
#define BROWS 32
#define NWAVES 8
#define CAP 128
#define NCT 16

typedef __attribute__((ext_vector_type(8))) short bf16x8;
typedef __attribute__((ext_vector_type(4))) float f32x4;

__device__ __forceinline__ unsigned int f2bf(float x) {
    unsigned int u = __builtin_bit_cast(unsigned int, x);
    return (u + 0x7FFFu + ((u >> 16) & 1u)) >> 16;   // RNE
}
__device__ __forceinline__ unsigned int pk2(float lo, float hi) {
    return f2bf(lo) | (f2bf(hi) << 16);
}

__global__ __launch_bounds__(256)
void cvt_bf16_kernel(const float* __restrict__ src, uint4* __restrict__ dst, int n8) {
    int i = blockIdx.x * 256 + threadIdx.x;
    if (i >= n8) return;
    const float4* s4 = reinterpret_cast<const float4*>(src);
    float4 a = s4[2 * i], b = s4[2 * i + 1];
    uint4 o;
    o.x = pk2(a.x, a.y); o.y = pk2(a.z, a.w);
    o.z = pk2(b.x, b.y); o.w = pk2(b.z, b.w);
    dst[i] = o;
}

__global__ __launch_bounds__(512)
void spx_main(const float* __restrict__ Q, const float* __restrict__ K,
              const float* __restrict__ V, float* __restrict__ O,
              const unsigned short* __restrict__ Qb,
              const unsigned short* __restrict__ Kb)
{
    __shared__ float s_wmax[NWAVES][BROWS];
    __shared__ float s_rmax[BROWS];
    __shared__ int   s_cnt[BROWS];
    __shared__ int   s_lcol[BROWS][CAP];   // 16 KB
    __shared__ float s_lval[BROWS][CAP];   // 16 KB

    const int t  = threadIdx.x;
    const int w  = t >> 6;
    const int l  = t & 63;
    const int lm = l & 15;       // col index within 16-tile
    const int lk = l >> 4;       // k-group / row-group

    int bid = blockIdx.x;
    if (((int)gridDim.x & 7) == 0)
        bid = (bid & 7) * ((int)gridDim.x >> 3) + (bid >> 3);   // XCD swizzle
    const int nrb  = S_LEN / BROWS;
    const int bh   = bid / nrb;
    const int rb   = bid % nrb;
    const int row0 = rb * BROWS;

    const size_t bhoff = (size_t)bh * S_LEN * DHEAD;
    const float* Qf = Q + bhoff;
    const float* Kf = K + bhoff;
    const float* Vf = V + bhoff;
    float*       Of = O + bhoff;

    if (t < BROWS) s_cnt[t] = 0;

    // ---- A fragments: Q[row0+rt*16+lm][kp*32 + lk*8 + 0..7] ----
    bf16x8 afrag[2][2];
    #pragma unroll
    for (int rt = 0; rt < 2; ++rt)
        #pragma unroll
        for (int kp = 0; kp < 2; ++kp)
            afrag[rt][kp] = *reinterpret_cast<const bf16x8*>(
                Qb + bhoff + (size_t)(row0 + rt * 16 + lm) * DHEAD + kp * 32 + lk * 8);

    const int col0 = w * 256;
    const unsigned short* KbB = Kb + bhoff;

    // ---- pass A: streaming MFMA, running row-max only ----
    float pm[2][4];
    #pragma unroll
    for (int rt = 0; rt < 2; ++rt)
        #pragma unroll
        for (int e = 0; e < 4; ++e) pm[rt][e] = -FLT_MAX;

    #pragma unroll 4
    for (int ct = 0; ct < NCT; ++ct) {
        const unsigned short* kp8 = KbB + (size_t)(col0 + ct * 16 + lm) * DHEAD;
        bf16x8 b0 = *reinterpret_cast<const bf16x8*>(kp8 + lk * 8);
        bf16x8 b1 = *reinterpret_cast<const bf16x8*>(kp8 + 32 + lk * 8);
        f32x4 a0 = (f32x4){0.f, 0.f, 0.f, 0.f};
        f32x4 a1 = (f32x4){0.f, 0.f, 0.f, 0.f};
        a0 = __builtin_amdgcn_mfma_f32_16x16x32_bf16(afrag[0][0], b0, a0, 0, 0, 0);
        a0 = __builtin_amdgcn_mfma_f32_16x16x32_bf16(afrag[0][1], b1, a0, 0, 0, 0);
        a1 = __builtin_amdgcn_mfma_f32_16x16x32_bf16(afrag[1][0], b0, a1, 0, 0, 0);
        a1 = __builtin_amdgcn_mfma_f32_16x16x32_bf16(afrag[1][1], b1, a1, 0, 0, 0);
        #pragma unroll
        for (int e = 0; e < 4; ++e) {
            pm[0][e] = fmaxf(pm[0][e], a0[e]);
            pm[1][e] = fmaxf(pm[1][e], a1[e]);
        }
    }
    // combine across the 16 col lanes (lm): xor 1,2,4,8
    #pragma unroll
    for (int o = 1; o < 16; o <<= 1)
        #pragma unroll
        for (int rt = 0; rt < 2; ++rt)
            #pragma unroll
            for (int e = 0; e < 4; ++e)
                pm[rt][e] = fmaxf(pm[rt][e], __shfl_xor(pm[rt][e], o));
    if (lm == 0) {
        #pragma unroll
        for (int rt = 0; rt < 2; ++rt)
            #pragma unroll
            for (int e = 0; e < 4; ++e)
                s_wmax[w][rt * 16 + lk * 4 + e] = pm[rt][e];
    }
    __syncthreads();
    if (t < BROWS) {
        float m = s_wmax[0][t];
        #pragma unroll
        for (int ww = 1; ww < NWAVES; ++ww) m = fmaxf(m, s_wmax[ww][t]);
        s_rmax[t] = m;
    }
    __syncthreads();

    // ---- pass B: re-stream MFMA, collect candidates {raw > rawmax-8.5} ----
    float thr[2][4];
    #pragma unroll
    for (int rt = 0; rt < 2; ++rt)
        #pragma unroll
        for (int e = 0; e < 4; ++e)
            thr[rt][e] = s_rmax[rt * 16 + lk * 4 + e] - 8.5f;

    #pragma unroll 4
    for (int ct = 0; ct < NCT; ++ct) {
        const unsigned short* kp8 = KbB + (size_t)(col0 + ct * 16 + lm) * DHEAD;
        bf16x8 b0 = *reinterpret_cast<const bf16x8*>(kp8 + lk * 8);
        bf16x8 b1 = *reinterpret_cast<const bf16x8*>(kp8 + 32 + lk * 8);
        f32x4 a0 = (f32x4){0.f, 0.f, 0.f, 0.f};
        f32x4 a1 = (f32x4){0.f, 0.f, 0.f, 0.f};
        a0 = __builtin_amdgcn_mfma_f32_16x16x32_bf16(afrag[0][0], b0, a0, 0, 0, 0);
        a0 = __builtin_amdgcn_mfma_f32_16x16x32_bf16(afrag[0][1], b1, a0, 0, 0, 0);
        a1 = __builtin_amdgcn_mfma_f32_16x16x32_bf16(afrag[1][0], b0, a1, 0, 0, 0);
        a1 = __builtin_amdgcn_mfma_f32_16x16x32_bf16(afrag[1][1], b1, a1, 0, 0, 0);
        #pragma unroll
        for (int e = 0; e < 4; ++e) {
            if (a0[e] > thr[0][e]) {
                int row = lk * 4 + e;
                int pos = atomicAdd(&s_cnt[row], 1);
                if (pos < CAP) s_lcol[row][pos] = col0 + ct * 16 + lm;
            }
            if (a1[e] > thr[1][e]) {
                int row = 16 + lk * 4 + e;
                int pos = atomicAdd(&s_cnt[row], 1);
                if (pos < CAP) s_lcol[row][pos] = col0 + ct * 16 + lm;
            }
        }
    }
    __syncthreads();

    // ---- phase 2: wave w handles rows w*4 .. w*4+3 sequentially ----
    for (int j = 0; j < 4; ++j) {
        const int r    = w * 4 + j;
        const int grow = row0 + r;
        const float qv = Qf[(size_t)grow * DHEAD + l];
        const int   nc = s_cnt[r];

        if (nc <= CAP) {
            const int n = nc;
            // fp32 cooperative recompute of candidate scores (divided units)
            float cv0 = -FLT_MAX, cv1 = -FLT_MAX;
            for (int i = 0; i < n; ++i) {
                const int c = s_lcol[r][i];                    // LDS broadcast
                float d = qv * Kf[(size_t)c * DHEAD + l];      // coalesced
                #pragma unroll
                for (int o = 1; o < 64; o <<= 1) d += __shfl_xor(d, o);
                d *= 0.125f;
                if (l == i)      cv0 = d;
                if (l + 64 == i) cv1 = d;
            }
            // Michelot: exact tau, finite convergence
            float tau = -3.0e38f; int last = -1;
            for (int it = 0; it < CAP + 2; ++it) {
                float sm = ((cv0 > tau) ? cv0 : 0.f) + ((cv1 > tau) ? cv1 : 0.f);
                int   c  = ((cv0 > tau) ? 1 : 0)     + ((cv1 > tau) ? 1 : 0);
                #pragma unroll
                for (int o = 1; o < 64; o <<= 1) {
                    sm += __shfl_xor(sm, o);
                    c  += __shfl_xor(c, o);
                }
                if (c == last) break;
                tau = (sm - 1.f) / (float)c;
                last = c;
            }
            // publish p-values for broadcast PV (same-wave LDS, no barrier)
            if (l < n)      s_lval[r][l]      = fmaxf(cv0 - tau, 0.f);
            if (l + 64 < n) s_lval[r][l + 64] = fmaxf(cv1 - tau, 0.f);
            float oacc = 0.f;
            for (int i = 0; i < n; ++i) {
                const float p = s_lval[r][i];                  // broadcast
                if (p > 0.f)                                    // uniform
                    oacc += p * Vf[(size_t)s_lcol[r][i] * DHEAD + l];
            }
            Of[(size_t)grow * DHEAD + l] = oacc;
        } else {
            // ---- dense fp32 fallback (correct for any data; never hit) ----
            float m = -FLT_MAX;
            for (int c0 = 0; c0 < S_LEN; c0 += 64) {
                const float* kp = Kf + (size_t)(c0 + l) * DHEAD;
                float s = 0.f;
                for (int d = 0; d < DHEAD; ++d)
                    s = fmaf(Qf[(size_t)grow * DHEAD + d], kp[d], s);
                m = fmaxf(m, s * 0.125f);
            }
            #pragma unroll
            for (int o = 1; o < 64; o <<= 1) m = fmaxf(m, __shfl_xor(m, o));
            float lo = m - 1.f, hi = m;
            for (int it = 0; it < 50; ++it) {
                const float mid = 0.5f * (lo + hi);
                float sm = 0.f;
                for (int c0 = 0; c0 < S_LEN; c0 += 64) {
                    const float* kp = Kf + (size_t)(c0 + l) * DHEAD;
                    float s = 0.f;
                    for (int d = 0; d < DHEAD; ++d)
                        s = fmaf(Qf[(size_t)grow * DHEAD + d], kp[d], s);
                    sm += fmaxf(s * 0.125f - mid, 0.f);
                }
                #pragma unroll
                for (int o = 1; o < 64; o <<= 1) sm += __shfl_xor(sm, o);
                if (sm > 1.f) lo = mid; else hi = mid;
            }
            float sm = 0.f; int c = 0;
            for (int c0 = 0; c0 < S_LEN; c0 += 64) {
                const float* kp = Kf + (size_t)(c0 + l) * DHEAD;
                float s = 0.f;
                for (int d = 0; d < DHEAD; ++d)
                    s = fmaf(Qf[(size_t)grow * DHEAD + d], kp[d], s);
                s *= 0.125f;
                if (s > lo) { sm += s; ++c; }
            }
            #pragma unroll
            for (int o = 1; o < 64; o <<= 1) { sm += __shfl_xor(sm, o); c += __shfl_xor(c, o); }
            const float tau = (sm - 1.f) / (float)c;
            float oacc = 0.f;
            for (int k = 0; k < S_LEN; ++k) {
                float d = qv * Kf[(size_t)k * DHEAD + l];
                #pragma unroll
                for (int o = 1; o < 64; o <<= 1) d += __shfl_xor(d, o);
                const float p = d * 0.125f - tau;
                if (p > 0.f) oacc += p * Vf[(size_t)k * DHEAD + l];
            }
            Of[(size_t)grow * DHEAD + l] = oacc;
        }
    }
}

extern "C" void kernel_launch(void* const* d_in, const int* in_sizes, int n_in,
                              void* d_out, int out_size, void* d_ws, size_t ws_size,
                              hipStream_t stream) {
    const float* q = (const float*)d_in[0];
    const float* k = (const float*)d_in[1];
    const float* v = (const float*)d_in[2];
    float* out = (float*)d_out;

    const int nElem = in_sizes[0];                     // B*H*S*D
    const int BH    = nElem / (S_LEN * DHEAD);
    const int grid  = BH * (S_LEN / BROWS);

    unsigned short* qb = (unsigned short*)d_ws;
    unsigned short* kb = qb + nElem;
    int n8 = nElem / 8;
    cvt_bf16_kernel<<<(n8 + 255) / 256, 256, 0, stream>>>(q, (uint4*)qb, n8);
    cvt_bf16_kernel<<<(n8 + 255) / 256, 256, 0, stream>>>(k, (uint4*)kb, n8);
    spx_main<<<grid, 512, 0, stream>>>(q, k, v, out, qb, kb);
}

// Round 6
// 355.027 us; speedup vs baseline: 8.5210x; 8.5210x over previous
//
#include <hip/hip_runtime.h>
#include <float.h>

// Sparsemax attention, fully-dense uniform pipeline, fp16 edition.
// B=2,H=16,S=2048,D=64 fp32, temperature 8.
//
// prep: K -> fp16 (ws), V -> fp16 TRANSPOSED VT[bh][64][2048] (ws).
// main (per block: 32 q-rows, 512 thr, 8 waves, 128 KB LDS):
//   phase 1: raw scores = Q K^T via mfma_f32_16x16x32_f16 -> fp16 LDS
//            (XOR-swizzled [32][2048]). Wave w owns cols [w*256,(w+1)*256).
//   sparsemax: wave w owns rows w*4..w*4+3 batched in registers:
//            row max -> Michelot iteration t' = (sum_{s>t} s - 8)/|{s>t}|
//            from t0 = max-8 (exact tau at fixpoint, wave-uniform break)
//            -> p = max(s-tau,0) fp16 back to LDS. No fallback needed.
//   phase 2: O = P V via MFMA; A=P from LDS, B=VT rows (contiguous f16x8).
//            Epilogue scales by 0.125 (temperature folded out).
// No atomics, no data-dependent lane divergence.

#define S_LEN 2048
#define DHEAD 64
#define BROWS 32
#define NWAVES 8

typedef _Float16 f16x8 __attribute__((ext_vector_type(8)));
typedef __attribute__((ext_vector_type(4))) float f32x4;
typedef __attribute__((ext_vector_type(8))) unsigned short u16x8;

__device__ __forceinline__ unsigned short f2h(float x) {
    return __builtin_bit_cast(unsigned short, (_Float16)x);
}
__device__ __forceinline__ float h2f(unsigned short u) {
    return (float)__builtin_bit_cast(_Float16, u);
}
__device__ __forceinline__ unsigned int pk2h(float lo, float hi) {
    return (unsigned int)f2h(lo) | ((unsigned int)f2h(hi) << 16);
}
__device__ __forceinline__ f16x8 cvt8h(float4 a, float4 b) {
    union { unsigned int u[4]; f16x8 v; } r;
    r.u[0] = pk2h(a.x, a.y); r.u[1] = pk2h(a.z, a.w);
    r.u[2] = pk2h(b.x, b.y); r.u[3] = pk2h(b.z, b.w);
    return r.v;
}

// swizzled LDS ushort index for scores/P[row][col]; flips idx bits 3-5 by
// row&7 -> kills the stride-4096B conflict on A-fragment ds_read_b128.
__device__ __forceinline__ int p_idx(int row, int col) {
    return (row * S_LEN + col) ^ ((row & 7) << 3);
}

__global__ __launch_bounds__(256)
void cvt_f16_kernel(const float* __restrict__ src, uint4* __restrict__ dst, int n8) {
    int i = blockIdx.x * 256 + threadIdx.x;
    if (i >= n8) return;
    const float4* s4 = reinterpret_cast<const float4*>(src);
    float4 a = s4[2 * i], b = s4[2 * i + 1];
    uint4 o;
    o.x = pk2h(a.x, a.y); o.y = pk2h(a.z, a.w);
    o.z = pk2h(b.x, b.y); o.w = pk2h(b.z, b.w);
    dst[i] = o;
}

// V[bh][2048][64] fp32 -> VT[bh][64][2048] fp16, 64x64 tiles via LDS
__global__ __launch_bounds__(256)
void vt_kernel(const float* __restrict__ V, unsigned short* __restrict__ VT) {
    __shared__ unsigned short tile[64][72];   // +8 pad
    const int t  = threadIdx.x;
    const int bh = blockIdx.x >> 5;           // 32 s-tiles per bh
    const int s0 = (blockIdx.x & 31) * 64;
    const float* Vb = V + ((size_t)bh * S_LEN + s0) * DHEAD;
    const int r = t >> 2, q = t & 3;
    #pragma unroll
    for (int j = 0; j < 4; ++j) {
        float4 v4 = *reinterpret_cast<const float4*>(Vb + (size_t)r * DHEAD + q * 16 + j * 4);
        tile[r][q * 16 + j * 4 + 0] = f2h(v4.x);
        tile[r][q * 16 + j * 4 + 1] = f2h(v4.y);
        tile[r][q * 16 + j * 4 + 2] = f2h(v4.z);
        tile[r][q * 16 + j * 4 + 3] = f2h(v4.w);
    }
    __syncthreads();
    const int d = t >> 2;
    union { unsigned short s[16]; u16x8 v[2]; } o;
    #pragma unroll
    for (int i = 0; i < 16; ++i) o.s[i] = tile[q * 16 + i][d];
    u16x8* dst = reinterpret_cast<u16x8*>(VT + ((size_t)bh * DHEAD + d) * S_LEN + s0 + q * 16);
    dst[0] = o.v[0];
    dst[1] = o.v[1];
}

__global__ __launch_bounds__(512)
void spx_main(const float* __restrict__ Q,
              const unsigned short* __restrict__ Kh,
              const unsigned short* __restrict__ VT,
              float* __restrict__ O)
{
    __shared__ unsigned short s_p[BROWS * S_LEN];   // 128 KB, swizzled

    const int t  = threadIdx.x;
    const int w  = t >> 6;
    const int l  = t & 63;
    const int lm = l & 15;
    const int lk = l >> 4;

    int bid = blockIdx.x;
    if (((int)gridDim.x & 7) == 0)
        bid = (bid & 7) * ((int)gridDim.x >> 3) + (bid >> 3);   // XCD swizzle
    const int nrb  = S_LEN / BROWS;                  // 64
    const int bh   = bid / nrb;
    const int row0 = (bid % nrb) * BROWS;

    const size_t bhoff = (size_t)bh * S_LEN * DHEAD;
    const float* Qf = Q + bhoff;
    const unsigned short* KhB = Kh + bhoff;
    const unsigned short* VTb = VT + bhoff;
    float* Of = O + bhoff;

    // ---- A fragments from fp32 Q (one-time, inline cvt) ----
    f16x8 afrag[2][2];
    #pragma unroll
    for (int rt = 0; rt < 2; ++rt)
        #pragma unroll
        for (int kp = 0; kp < 2; ++kp) {
            const float* qp = Qf + (size_t)(row0 + rt * 16 + lm) * DHEAD + kp * 32 + lk * 8;
            afrag[rt][kp] = cvt8h(*reinterpret_cast<const float4*>(qp),
                                  *reinterpret_cast<const float4*>(qp + 4));
        }

    // ---- phase 1: raw scores -> fp16 LDS ----
    const int col0 = w * (S_LEN / NWAVES);           // 256 cols per wave
    #pragma unroll 4
    for (int ct = 0; ct < 16; ++ct) {
        const int kc = col0 + ct * 16 + lm;
        const unsigned short* kp8 = KhB + (size_t)kc * DHEAD;
        f16x8 b0 = *reinterpret_cast<const f16x8*>(kp8 + lk * 8);
        f16x8 b1 = *reinterpret_cast<const f16x8*>(kp8 + 32 + lk * 8);
        f32x4 a0 = (f32x4){0.f, 0.f, 0.f, 0.f};
        f32x4 a1 = (f32x4){0.f, 0.f, 0.f, 0.f};
        a0 = __builtin_amdgcn_mfma_f32_16x16x32_f16(afrag[0][0], b0, a0, 0, 0, 0);
        a0 = __builtin_amdgcn_mfma_f32_16x16x32_f16(afrag[0][1], b1, a0, 0, 0, 0);
        a1 = __builtin_amdgcn_mfma_f32_16x16x32_f16(afrag[1][0], b0, a1, 0, 0, 0);
        a1 = __builtin_amdgcn_mfma_f32_16x16x32_f16(afrag[1][1], b1, a1, 0, 0, 0);
        #pragma unroll
        for (int e = 0; e < 4; ++e) {
            const int rl = lk * 4 + e;
            s_p[p_idx(rl,      kc)] = f2h(a0[e]);
            s_p[p_idx(rl + 16, kc)] = f2h(a1[e]);
        }
    }
    __syncthreads();

    // ---- sparsemax: wave w owns rows w*4..w*4+3, batched ----
    {
        const int r0 = w * 4;
        float sc[4][32];
        #pragma unroll
        for (int j = 0; j < 4; ++j)
            #pragma unroll
            for (int c = 0; c < 4; ++c) {
                u16x8 v = *reinterpret_cast<const u16x8*>(&s_p[p_idx(r0 + j, c * 512 + l * 8)]);
                #pragma unroll
                for (int e = 0; e < 8; ++e) sc[j][c * 8 + e] = h2f(v[e]);
            }

        // row max (raw units)
        float mx[4];
        #pragma unroll
        for (int j = 0; j < 4; ++j) {
            float m = sc[j][0];
            #pragma unroll
            for (int i = 1; i < 32; ++i) m = fmaxf(m, sc[j][i]);
            mx[j] = m;
        }
        #pragma unroll
        for (int o = 1; o < 64; o <<= 1)
            #pragma unroll
            for (int j = 0; j < 4; ++j) mx[j] = fmaxf(mx[j], __shfl_xor(mx[j], o));

        // Michelot: t0 = max-8 (superset of support); t' = (sum_{s>t}-8)/cnt;
        // exact tau at fixpoint; monotone increasing; wave-uniform break.
        float tv[4];
        int   last[4] = {-1, -1, -1, -1};
        #pragma unroll
        for (int j = 0; j < 4; ++j) tv[j] = mx[j] - 8.f;
        for (int it = 0; it < 32; ++it) {
            float sm[4], cn[4];
            #pragma unroll
            for (int j = 0; j < 4; ++j) {
                float s = 0.f, c = 0.f;
                #pragma unroll
                for (int i = 0; i < 32; ++i) {
                    const bool in = sc[j][i] > tv[j];
                    s += in ? sc[j][i] : 0.f;
                    c += in ? 1.f : 0.f;
                }
                sm[j] = s; cn[j] = c;
            }
            #pragma unroll
            for (int o = 1; o < 64; o <<= 1)
                #pragma unroll
                for (int j = 0; j < 4; ++j) {
                    sm[j] += __shfl_xor(sm[j], o);
                    cn[j] += __shfl_xor(cn[j], o);
                }
            bool done = true;
            #pragma unroll
            for (int j = 0; j < 4; ++j) {
                const int ci = (int)cn[j];
                if (ci != last[j]) done = false;
                last[j] = ci;
                tv[j] = (sm[j] - 8.f) / cn[j];
            }
            if (done) break;
        }

        // p = max(s - tau, 0) -> fp16 back into LDS (same swizzled slots)
        #pragma unroll
        for (int j = 0; j < 4; ++j) {
            #pragma unroll
            for (int c = 0; c < 4; ++c) {
                union { unsigned int u[4]; u16x8 v; } pw;
                #pragma unroll
                for (int e = 0; e < 4; ++e) {
                    float p0 = fmaxf(sc[j][c * 8 + 2 * e]     - tv[j], 0.f);
                    float p1 = fmaxf(sc[j][c * 8 + 2 * e + 1] - tv[j], 0.f);
                    pw.u[e] = pk2h(p0, p1);
                }
                *reinterpret_cast<u16x8*>(&s_p[p_idx(r0 + j, c * 512 + l * 8)]) = pw.v;
            }
        }
    }
    __syncthreads();

    // ---- phase 2: O = P V ; wave w -> out tile (mt = w>>2, nt = w&3) ----
    {
        const int mt = w >> 2;                 // 0..1  (rows mt*16..)
        const int nt = w & 3;                  // 0..3  (cols nt*16..)
        const unsigned short* vrow = VTb + (size_t)(nt * 16 + lm) * S_LEN;
        f32x4 acc0 = (f32x4){0.f, 0.f, 0.f, 0.f};
        f32x4 acc1 = (f32x4){0.f, 0.f, 0.f, 0.f};
        #pragma unroll 8
        for (int ks = 0; ks < S_LEN / 32; ks += 2) {
            f16x8 pa0 = *reinterpret_cast<const f16x8*>(
                &s_p[p_idx(mt * 16 + lm, ks * 32 + lk * 8)]);
            f16x8 pb0 = *reinterpret_cast<const f16x8*>(vrow + ks * 32 + lk * 8);
            f16x8 pa1 = *reinterpret_cast<const f16x8*>(
                &s_p[p_idx(mt * 16 + lm, (ks + 1) * 32 + lk * 8)]);
            f16x8 pb1 = *reinterpret_cast<const f16x8*>(vrow + (ks + 1) * 32 + lk * 8);
            acc0 = __builtin_amdgcn_mfma_f32_16x16x32_f16(pa0, pb0, acc0, 0, 0, 0);
            acc1 = __builtin_amdgcn_mfma_f32_16x16x32_f16(pa1, pb1, acc1, 0, 0, 0);
        }
        #pragma unroll
        for (int e = 0; e < 4; ++e) {
            const int grow = row0 + mt * 16 + lk * 4 + e;
            Of[(size_t)grow * DHEAD + nt * 16 + lm] = (acc0[e] + acc1[e]) * 0.125f;
        }
    }
}

extern "C" void kernel_launch(void* const* d_in, const int* in_sizes, int n_in,
                              void* d_out, int out_size, void* d_ws, size_t ws_size,
                              hipStream_t stream) {
    const float* q = (const float*)d_in[0];
    const float* k = (const float*)d_in[1];
    const float* v = (const float*)d_in[2];
    float* out = (float*)d_out;

    const int nElem = in_sizes[0];                    // B*H*S*D
    const int BH    = nElem / (S_LEN * DHEAD);

    unsigned short* kh = (unsigned short*)d_ws;
    unsigned short* vt = kh + nElem;

    const int n8 = nElem / 8;
    cvt_f16_kernel<<<(n8 + 255) / 256, 256, 0, stream>>>(k, (uint4*)kh, n8);
    vt_kernel<<<BH * (S_LEN / 64), 256, 0, stream>>>(v, vt);
    spx_main<<<BH * (S_LEN / BROWS), 512, 0, stream>>>(q, kh, vt, out);
}